// Round 4
// baseline (341.089 us; speedup 1.0000x reference)
//
#include <hip/hip_runtime.h>

#define HID 256
#define NFEAT 8
#define SLEN 2048

typedef float v4f __attribute__((ext_vector_type(4)));

__device__ __forceinline__ float wave_sum(float v) {
#pragma unroll
    for (int o = 32; o > 0; o >>= 1) v += __shfl_xor(v, o, 64);
    return v;
}

// ------------------------------------------------------------------
// K1: build tables.
//  blocks 0..SLEN-1 (1 wave each): per-s row
//    base2[s][h] = sum_f bias[f][h] + ie[s][h]          (2 MB)
//    tab[s*16 + {0:Sb0, 1:Qb0, 2:Sb0on, 3:Sb0off, 4..11: Sb0W_f}]
//  block SLEN (1 wave): constant Gram table cst[96]:
//    [0..63] WW[f*8+g]=Σ_h W_f W_g, [64..71] SW_f=Σ_h W_f,
//    [72..79] SonW_f, [80..87] SoffW_f, [88..91] {Son,Soff,Son2,Soff2}
// ------------------------------------------------------------------
__global__ __launch_bounds__(64) void k1_build(
    const float* __restrict__ bias, const float* __restrict__ ie,
    const float* __restrict__ W,    const float* __restrict__ fon,
    const float* __restrict__ foff,
    float* __restrict__ base2, float* __restrict__ tab, float* __restrict__ cst)
{
    const int lane = threadIdx.x;
    const int h0 = lane << 2;

    float wc[NFEAT][4];
#pragma unroll
    for (int f = 0; f < NFEAT; ++f) {
        const float4 w4 = *reinterpret_cast<const float4*>(W + f * HID + h0);
        wc[f][0] = w4.x; wc[f][1] = w4.y; wc[f][2] = w4.z; wc[f][3] = w4.w;
    }
    const float4 on4 = *reinterpret_cast<const float4*>(fon  + h0);
    const float4 of4 = *reinterpret_cast<const float4*>(foff + h0);
    const float on[4]  = {on4.x, on4.y, on4.z, on4.w};
    const float off[4] = {of4.x, of4.y, of4.z, of4.w};

    if (blockIdx.x < SLEN) {
        const int s = blockIdx.x;
        const float4 e4 = *reinterpret_cast<const float4*>(ie + (size_t)s * HID + h0);
        float b0[4] = {e4.x, e4.y, e4.z, e4.w};
#pragma unroll
        for (int f = 0; f < NFEAT; ++f) {
            const float4 b4 = *reinterpret_cast<const float4*>(bias + f * HID + h0);
            b0[0] += b4.x; b0[1] += b4.y; b0[2] += b4.z; b0[3] += b4.w;
        }
        float r[12];
        r[0] = b0[0] + b0[1] + b0[2] + b0[3];
        r[1] = b0[0]*b0[0] + b0[1]*b0[1] + b0[2]*b0[2] + b0[3]*b0[3];
        r[2] = b0[0]*on[0] + b0[1]*on[1] + b0[2]*on[2] + b0[3]*on[3];
        r[3] = b0[0]*off[0]+ b0[1]*off[1]+ b0[2]*off[2]+ b0[3]*off[3];
#pragma unroll
        for (int f = 0; f < NFEAT; ++f)
            r[4+f] = b0[0]*wc[f][0] + b0[1]*wc[f][1] + b0[2]*wc[f][2] + b0[3]*wc[f][3];
#pragma unroll
        for (int i = 0; i < 12; ++i) r[i] = wave_sum(r[i]);

        float4 b04 = make_float4(b0[0], b0[1], b0[2], b0[3]);
        *reinterpret_cast<float4*>(base2 + (size_t)s * HID + h0) = b04;
        if (lane == 0) {
#pragma unroll
            for (int i = 0; i < 12; ++i) tab[s * 16 + i] = r[i];
        }
    } else {
        float r[92];
#pragma unroll
        for (int f = 0; f < NFEAT; ++f)
#pragma unroll
            for (int g = 0; g < NFEAT; ++g)
                r[f*8+g] = wc[f][0]*wc[g][0] + wc[f][1]*wc[g][1]
                         + wc[f][2]*wc[g][2] + wc[f][3]*wc[g][3];
#pragma unroll
        for (int f = 0; f < NFEAT; ++f)
            r[64+f] = wc[f][0] + wc[f][1] + wc[f][2] + wc[f][3];
#pragma unroll
        for (int f = 0; f < NFEAT; ++f)
            r[72+f] = on[0]*wc[f][0] + on[1]*wc[f][1] + on[2]*wc[f][2] + on[3]*wc[f][3];
#pragma unroll
        for (int f = 0; f < NFEAT; ++f)
            r[80+f] = off[0]*wc[f][0] + off[1]*wc[f][1] + off[2]*wc[f][2] + off[3]*wc[f][3];
        r[88] = on[0] + on[1] + on[2] + on[3];
        r[89] = off[0]+ off[1]+ off[2]+ off[3];
        r[90] = on[0]*on[0] + on[1]*on[1] + on[2]*on[2] + on[3]*on[3];
        r[91] = off[0]*off[0]+ off[1]*off[1]+ off[2]*off[2]+ off[3]*off[3];
#pragma unroll
        for (int i = 0; i < 92; ++i) r[i] = wave_sum(r[i]);
        if (lane == 0) {
#pragma unroll
            for (int i = 0; i < 92; ++i) cst[i] = r[i];
        }
    }
}

// ------------------------------------------------------------------
// K2: per-token (mu, rstd) via the Gram identity. 1 thread / token.
// lane-consecutive s -> x/mask/musig fully coalesced; tab gather is
// L2-resident; cst loads wave-uniform.
// ------------------------------------------------------------------
__global__ __launch_bounds__(256, 4) void k2_stats(
    const float* __restrict__ x, const int* __restrict__ mask,
    const float* __restrict__ tab, const float* __restrict__ cst,
    float2* __restrict__ musig, int Bdim)
{
    const int tid   = blockIdx.x * blockDim.x + threadIdx.x;
    const int lane  = tid & 63;
    const int gwave = tid >> 6;
    const int b     = gwave >> 5;             // 32 waves per batch row
    const int s     = ((gwave & 31) << 6) + lane;
    if (b >= Bdim) return;
    const int t = b * SLEN + s;

    const float4 x0 = *reinterpret_cast<const float4*>(x + (size_t)t * NFEAT);
    const float4 x1 = *reinterpret_cast<const float4*>(x + (size_t)t * NFEAT + 4);
    const float xs[NFEAT] = {x0.x, x0.y, x0.z, x0.w, x1.x, x1.y, x1.z, x1.w};
    const int m = mask[t];
    const float fm1 = (m == 1) ? 1.0f : 0.0f;
    const float fm2 = (m == 2) ? 1.0f : 0.0f;

    const float4* tab4 = reinterpret_cast<const float4*>(tab + (size_t)s * 16);
    const float4 t0 = tab4[0];                 // Sb0, Qb0, Sb0on, Sb0off
    const float4 q0 = tab4[1];
    const float4 q1 = tab4[2];
    float qf[NFEAT] = {q0.x, q0.y, q0.z, q0.w, q1.x, q1.y, q1.z, q1.w};

    const float4* c4 = reinterpret_cast<const float4*>(cst);
    const float4 sw0 = c4[16], sw1 = c4[17];
    const float4 so0 = c4[18], so1 = c4[19];   // SonW
    const float4 sf0 = c4[20], sf1 = c4[21];   // SoffW
    const float4 sc  = c4[22];                 // Son, Soff, Son2, Soff2
    const float sw[NFEAT]   = {sw0.x, sw0.y, sw0.z, sw0.w, sw1.x, sw1.y, sw1.z, sw1.w};
    const float sonw[NFEAT] = {so0.x, so0.y, so0.z, so0.w, so1.x, so1.y, so1.z, so1.w};
    const float sofw[NFEAT] = {sf0.x, sf0.y, sf0.z, sf0.w, sf1.x, sf1.y, sf1.z, sf1.w};

#pragma unroll
    for (int f = 0; f < NFEAT; ++f)
        qf[f] += fm1 * sonw[f] + fm2 * sofw[f];

    float s1 = t0.x + fm1 * sc.x + fm2 * sc.y;
#pragma unroll
    for (int f = 0; f < NFEAT; ++f) s1 = fmaf(xs[f], sw[f], s1);

    float s2 = t0.y + fm1 * (2.0f * t0.z + sc.z) + fm2 * (2.0f * t0.w + sc.w);
#pragma unroll
    for (int f = 0; f < NFEAT; ++f) {
        const float4 wa = c4[f * 2];
        const float4 wb = c4[f * 2 + 1];
        float tf = 2.0f * qf[f];
        tf = fmaf(wa.x, xs[0], tf); tf = fmaf(wa.y, xs[1], tf);
        tf = fmaf(wa.z, xs[2], tf); tf = fmaf(wa.w, xs[3], tf);
        tf = fmaf(wb.x, xs[4], tf); tf = fmaf(wb.y, xs[5], tf);
        tf = fmaf(wb.z, xs[6], tf); tf = fmaf(wb.w, xs[7], tf);
        s2 = fmaf(xs[f], tf, s2);
    }

    const float mu   = s1 * (1.0f / HID);
    const float var  = s2 * (1.0f / HID) - mu * mu;
    const float rstd = rsqrtf(var + 1e-5f);
    musig[t] = make_float2(mu, rstd);
}

// ------------------------------------------------------------------
// K3: streaming apply. 1 token per wave pass, unroll x2, nt stores.
// ------------------------------------------------------------------
__global__ __launch_bounds__(256, 4) void k3_apply(
    const float* __restrict__ x, const int* __restrict__ mask,
    const float* __restrict__ W, const float* __restrict__ base2,
    const float* __restrict__ fon, const float* __restrict__ foff,
    const float* __restrict__ gamma, const float* __restrict__ beta,
    const float2* __restrict__ musig, float* __restrict__ out, int ntokens)
{
    const int lane = threadIdx.x & 63;
    const int wavesPerBlock = blockDim.x >> 6;
    const int gwave = blockIdx.x * wavesPerBlock + (threadIdx.x >> 6);
    const int nwaves = gridDim.x * wavesPerBlock;
    const int h0 = lane << 2;

    float wc[NFEAT][4];
#pragma unroll
    for (int f = 0; f < NFEAT; ++f) {
        const float4 w4 = *reinterpret_cast<const float4*>(W + f * HID + h0);
        wc[f][0] = w4.x; wc[f][1] = w4.y; wc[f][2] = w4.z; wc[f][3] = w4.w;
    }
    const float4 g4  = *reinterpret_cast<const float4*>(gamma + h0);
    const float4 be4 = *reinterpret_cast<const float4*>(beta  + h0);
    const float4 on4 = *reinterpret_cast<const float4*>(fon   + h0);
    const float4 of4 = *reinterpret_cast<const float4*>(foff  + h0);

    auto process = [&](int t) {
        const int s = t & (SLEN - 1);
        const float2 ms = musig[t];
        float4 acc = *reinterpret_cast<const float4*>(base2 + (size_t)s * HID + h0);
        const float4 x0 = *reinterpret_cast<const float4*>(x + (size_t)t * NFEAT);
        const float4 x1 = *reinterpret_cast<const float4*>(x + (size_t)t * NFEAT + 4);
        const int m = mask[t];
        if (m == 1) {        // wave-uniform branch
            acc.x += on4.x; acc.y += on4.y; acc.z += on4.z; acc.w += on4.w;
        } else if (m == 2) {
            acc.x += of4.x; acc.y += of4.y; acc.z += of4.z; acc.w += of4.w;
        }
        const float xs[NFEAT] = {x0.x, x0.y, x0.z, x0.w, x1.x, x1.y, x1.z, x1.w};
#pragma unroll
        for (int f = 0; f < NFEAT; ++f) {
            acc.x = fmaf(xs[f], wc[f][0], acc.x);
            acc.y = fmaf(xs[f], wc[f][1], acc.y);
            acc.z = fmaf(xs[f], wc[f][2], acc.z);
            acc.w = fmaf(xs[f], wc[f][3], acc.w);
        }
        v4f o;
        o.x = (acc.x - ms.x) * ms.y * g4.x + be4.x;
        o.y = (acc.y - ms.x) * ms.y * g4.y + be4.y;
        o.z = (acc.z - ms.x) * ms.y * g4.z + be4.z;
        o.w = (acc.w - ms.x) * ms.y * g4.w + be4.w;
        __builtin_nontemporal_store(o, reinterpret_cast<v4f*>(out + (size_t)t * HID + h0));
    };

    int t = gwave;
    for (; t + nwaves < ntokens; t += 2 * nwaves) {
        process(t);
        process(t + nwaves);
    }
    if (t < ntokens) process(t);
}

extern "C" void kernel_launch(void* const* d_in, const int* in_sizes, int n_in,
                              void* d_out, int out_size, void* d_ws, size_t ws_size,
                              hipStream_t stream) {
    const float* x     = (const float*)d_in[0];
    const int*   mask  = (const int*)  d_in[1];
    const float* W     = (const float*)d_in[2];
    const float* bias  = (const float*)d_in[3];
    const float* ie    = (const float*)d_in[4];
    const float* fon   = (const float*)d_in[5];
    const float* foff  = (const float*)d_in[6];
    const float* gamma = (const float*)d_in[7];
    const float* beta  = (const float*)d_in[8];
    float* out = (float*)d_out;

    const int ntokens = in_sizes[0] / NFEAT;   // B*S
    const int Bdim    = ntokens / SLEN;        // 128

    // workspace layout (256-B aligned regions)
    char* ws = (char*)d_ws;
    float*  base2 = (float*)(ws);                        // 2 MiB
    float*  tab   = (float*)(ws + (1u << 21));           // 128 KiB (pad to 256 KiB)
    float*  cst   = (float*)(ws + (1u << 21) + (1u << 18)); // 384 B (pad to 64 KiB)
    float2* musig = (float2*)(ws + (1u << 21) + (1u << 18) + (1u << 16)); // 2 MiB

    // K1: tables (2048 s-rows + 1 const block), 1 wave per block
    k1_build<<<SLEN + 1, 64, 0, stream>>>(bias, ie, W, fon, foff, base2, tab, cst);

    // K2: per-token stats, 1 thread per token, coalesced
    {
        const int blocks = (Bdim * 32 * 64) / 256;   // = Bdim*8
        k2_stats<<<blocks, 256, 0, stream>>>(x, mask, tab, cst, musig, Bdim);
    }

    // K3: streaming apply
    k3_apply<<<2048, 256, 0, stream>>>(
        x, mask, W, base2, fon, foff, gamma, beta, musig, out, ntokens);
}